// Round 13
// baseline (165.806 us; speedup 1.0000x reference)
//
#include <hip/hip_runtime.h>
#include <hip/hip_cooperative_groups.h>

namespace cg = cooperative_groups;

#define B_    4
#define C_    640
#define H_    64
#define W_    64
#define NT    512       // 8 waves
#define G_    8         // waves per block
#define CPG   40        // channels per wave
#define CHALF 320       // channels per block (half)

// Block decode: XCD x owns rows [x*8, x*8+8); both channel-halves of a row on
// the same XCD (partner = n ^ 64; xcd bits 0-2 unchanged). Bijective over [0,512).
__device__ __forceinline__ void decode_bhs(int n, int& b, int& h, int& s) {
    const int xcd = n & 7;
    const int i   = n >> 3;          // 0..63
    h = xcd * 8 + (i & 7);
    s = (i >> 3) & 1;                // bit 6 of n
    b = i >> 4;
}

// Accumulate one Fwarp row (4 px in r) against ft4 into a[12] (3 col-offsets x 4 px).
__device__ __forceinline__ void row_acc(const float4 ft4, const float4 r,
                                        const int l16, float* a) {
    const float pw = __shfl_up(r.w, 1, 64);     // lane l-1's elem 3
    const float nx = __shfl_down(r.x, 1, 64);   // lane l+1's elem 0
    const float vL0 = (l16 == 0)  ? r.x : pw;   // col 0 replicate
    const float vR3 = (l16 == 15) ? r.w : nx;   // col 63 replicate
    a[0]  = fmaf(ft4.x, vL0, a[0]);             // cc = col-1
    a[1]  = fmaf(ft4.y, r.x, a[1]);
    a[2]  = fmaf(ft4.z, r.y, a[2]);
    a[3]  = fmaf(ft4.w, r.z, a[3]);
    a[4]  = fmaf(ft4.x, r.x, a[4]);             // cc = center
    a[5]  = fmaf(ft4.y, r.y, a[5]);
    a[6]  = fmaf(ft4.z, r.z, a[6]);
    a[7]  = fmaf(ft4.w, r.w, a[7]);
    a[8]  = fmaf(ft4.x, r.y, a[8]);             // cc = col+1
    a[9]  = fmaf(ft4.y, r.z, a[9]);
    a[10] = fmaf(ft4.z, r.w, a[10]);
    a[11] = fmaf(ft4.w, vR3, a[11]);
}

// Weighted sum of one Fwarp row into fwv[4]; at = attn[4px][9], r3 = 3*row.
__device__ __forceinline__ void row_fw(const float4 r, const int l16,
                                       const float* at, const int r3, float* fwv) {
    const float pw = __shfl_up(r.w, 1, 64);
    const float nx = __shfl_down(r.x, 1, 64);
    const float vL0 = (l16 == 0)  ? r.x : pw;
    const float vR3 = (l16 == 15) ? r.w : nx;
    fwv[0] += at[0*9+r3]*vL0 + at[0*9+r3+1]*r.x + at[0*9+r3+2]*r.y;
    fwv[1] += at[1*9+r3]*r.x + at[1*9+r3+1]*r.y + at[1*9+r3+2]*r.z;
    fwv[2] += at[2*9+r3]*r.y + at[2*9+r3+1]*r.z + at[2*9+r3+2]*r.w;
    fwv[3] += at[3*9+r3]*r.z + at[3*9+r3+1]*r.w + at[3*9+r3+2]*vR3;
}

// ---------------------------------------------------------------------------
// Shared phase bodies (used by the cooperative kernel and the 2-kernel fallback)
__device__ __forceinline__ void phase1_stream(
    const float* ftp, const float* q0p, const float* q1p, const float* q2p,
    const float* lds_cw, int c0, int sub, int l, int l16, int g, int w0, int t,
    float (*lds_sim)[W_][9], float (*lds_PT)[4][W_],
    float* simp, float* ptp, size_t r2i, size_t cs)
{
    float acc[36], Pp[12], T4[4];
    #pragma unroll
    for (int i = 0; i < 36; ++i) acc[i] = 0.f;
    #pragma unroll
    for (int i = 0; i < 12; ++i) Pp[i] = 0.f;
    #pragma unroll
    for (int i = 0; i < 4; ++i) T4[i] = 0.f;

    #pragma unroll 2
    for (int k = 0; k < CPG; k += 4) {
        const size_t off = (size_t)k * cs;
        const float4 ft4 = *(const float4*)(ftp + off);
        const float4 r0  = *(const float4*)(q0p + off);
        const float4 r1  = *(const float4*)(q1p + off);
        const float4 r2  = *(const float4*)(q2p + off);
        row_acc(ft4, r0, l16, &acc[0]);
        row_acc(ft4, r1, l16, &acc[12]);
        row_acc(ft4, r2, l16, &acc[24]);
        const int c = c0 + k + sub;
        const float wF = lds_cw[c];
        const float wT = lds_cw[C_ + c];
        Pp[0] = fmaf(wF, r0.x, Pp[0]); Pp[1]  = fmaf(wF, r0.y, Pp[1]);
        Pp[2] = fmaf(wF, r0.z, Pp[2]); Pp[3]  = fmaf(wF, r0.w, Pp[3]);
        Pp[4] = fmaf(wF, r1.x, Pp[4]); Pp[5]  = fmaf(wF, r1.y, Pp[5]);
        Pp[6] = fmaf(wF, r1.z, Pp[6]); Pp[7]  = fmaf(wF, r1.w, Pp[7]);
        Pp[8] = fmaf(wF, r2.x, Pp[8]); Pp[9]  = fmaf(wF, r2.y, Pp[9]);
        Pp[10]= fmaf(wF, r2.z, Pp[10]);Pp[11] = fmaf(wF, r2.w, Pp[11]);
        T4[0] = fmaf(wT, ft4.x, T4[0]); T4[1] = fmaf(wT, ft4.y, T4[1]);
        T4[2] = fmaf(wT, ft4.z, T4[2]); T4[3] = fmaf(wT, ft4.w, T4[3]);
    }

    #pragma unroll
    for (int i = 0; i < 36; ++i) {
        acc[i] += __shfl_xor(acc[i], 16, 64);
        acc[i] += __shfl_xor(acc[i], 32, 64);
    }
    #pragma unroll
    for (int i = 0; i < 12; ++i) {
        Pp[i] += __shfl_xor(Pp[i], 16, 64);
        Pp[i] += __shfl_xor(Pp[i], 32, 64);
    }
    #pragma unroll
    for (int i = 0; i < 4; ++i) {
        T4[i] += __shfl_xor(T4[i], 16, 64);
        T4[i] += __shfl_xor(T4[i], 32, 64);
    }

    // STATIC-index LDS write (rule #20: px is an unroll constant)
    if (l < 16) {
        #pragma unroll
        for (int px = 0; px < 4; ++px) {
            #pragma unroll
            for (int r = 0; r < 3; ++r) {
                #pragma unroll
                for (int cc = 0; cc < 3; ++cc)
                    lds_sim[g][w0 + px][r * 3 + cc] = acc[r * 12 + cc * 4 + px];
                lds_PT[g][r][w0 + px] = Pp[r * 4 + px];
            }
            lds_PT[g][3][w0 + px] = T4[px];
        }
    }
    __syncthreads();

    // block-level reduce across the 8 waves -> ws partials (own half)
    float* sp = simp + r2i * (W_ * 9);
    for (int idx = t; idx < W_ * 9; idx += NT) {
        const int ww = idx / 9, q = idx % 9;
        float v = 0.f;
        #pragma unroll
        for (int gg = 0; gg < G_; ++gg) v += lds_sim[gg][ww][q];
        sp[idx] = v;
    }
    if (t < 4 * W_) {
        const int r = t >> 6, ww = t & 63;
        float v = 0.f;
        #pragma unroll
        for (int gg = 0; gg < G_; ++gg) v += lds_PT[gg][r][ww];
        ptp[r2i * (4 * W_) + t] = v;
    }
}

__device__ __forceinline__ void phase2_out(
    const float* ftp, const float* q0p, const float* q1p, const float* q2p,
    float* outp, const float* simp, const float* ptp, const float* cb,
    const float (*lds_msk)[W_], float (*lds_attn)[9], float (*lds_Pf)[W_],
    float* lds_lam, int t, int l16, int w0, size_t bh2, size_t cs)
{
    const float* sp0 = simp + (bh2 + 0) * (W_ * 9);
    const float* sp1 = simp + (bh2 + 1) * (W_ * 9);
    for (int idx = t; idx < W_ * 9; idx += NT) {
        const int ww = idx / 9, q = idx % 9;
        float v = (sp0[idx] + sp1[idx]) * 0.03952847075210474f;  // 1/sqrt(640)
        const int r = q / 3, j = q % 3;
        int col = ww + j - 1;
        col = col < 0 ? 0 : (col > W_ - 1 ? W_ - 1 : col);
        if (lds_msk[r][col] == 1.0f) v = -1e9f;
        lds_attn[ww][q] = v;
    }
    if (t < 4 * W_) {
        lds_Pf[t >> 6][t & 63] =
            ptp[(bh2 + 0) * (4 * W_) + t] + ptp[(bh2 + 1) * (4 * W_) + t];
    }
    __syncthreads();

    if (t < W_) {
        float v[9];
        float mx = -3e38f;
        bool valid = false;
        #pragma unroll
        for (int q = 0; q < 9; ++q) {
            v[q] = lds_attn[t][q];
            if (v[q] > -5e8f) valid = true;
            mx = fmaxf(mx, v[q]);
        }
        float a9[9];
        if (!valid) {
            #pragma unroll
            for (int q = 0; q < 9; ++q) a9[q] = 0.f;
        } else {
            float sum = 0.f;
            #pragma unroll
            for (int q = 0; q < 9; ++q) { a9[q] = expf(v[q] - mx); sum += a9[q]; }
            const float inv = 1.f / sum;
            #pragma unroll
            for (int q = 0; q < 9; ++q) a9[q] *= inv;
        }
        #pragma unroll
        for (int q = 0; q < 9; ++q) lds_attn[t][q] = a9[q];

        float lamF = 0.f;
        #pragma unroll
        for (int r = 0; r < 3; ++r)
            #pragma unroll
            for (int j = 0; j < 3; ++j) {
                int col = t + j - 1;
                col = col < 0 ? 0 : (col > W_ - 1 ? W_ - 1 : col);
                lamF = fmaf(a9[r * 3 + j], lds_Pf[r][col], lamF);
            }
        const float d = lds_Pf[3][t] + lamF + cb[0];
        lds_lam[t] = 1.f / (1.f + expf(-d));
    }
    __syncthreads();

    float at[36];
    #pragma unroll
    for (int px = 0; px < 4; ++px)
        #pragma unroll
        for (int q = 0; q < 9; ++q) at[px * 9 + q] = lds_attn[w0 + px][q];
    float lam4[4], oml4[4];
    #pragma unroll
    for (int px = 0; px < 4; ++px) {
        lam4[px] = lds_lam[w0 + px];
        oml4[px] = 1.f - lam4[px];
    }

    #pragma unroll 2
    for (int k = 0; k < CPG; k += 4) {
        const size_t off = (size_t)k * cs;
        const float4 ft4 = *(const float4*)(ftp + off);
        const float4 r0  = *(const float4*)(q0p + off);
        const float4 r1  = *(const float4*)(q1p + off);
        const float4 r2  = *(const float4*)(q2p + off);
        float fwv[4] = {0.f, 0.f, 0.f, 0.f};
        row_fw(r0, l16, at, 0, fwv);
        row_fw(r1, l16, at, 3, fwv);
        row_fw(r2, l16, at, 6, fwv);
        float4 o;
        o.x = lam4[0] * ft4.x + oml4[0] * fwv[0];
        o.y = lam4[1] * ft4.y + oml4[1] * fwv[1];
        o.z = lam4[2] * ft4.z + oml4[2] * fwv[2];
        o.w = lam4[3] * ft4.w + oml4[3] * fwv[3];
        *(float4*)(outp + off) = o;
    }
}

// ===========================================================================
// Cooperative merged kernel: phase1 -> grid.sync() -> phase2.
__global__ __launch_bounds__(NT, 4) void nca_coop(
    const float* __restrict__ Ft, const float* __restrict__ Fwp,
    const float* __restrict__ mask,
    const float* __restrict__ cw, const float* __restrict__ cb,
    float* __restrict__ simp, float* __restrict__ ptp,
    float* __restrict__ out)
{
    __shared__ float lds_cw[2 * C_];        // 5 KB
    __shared__ float lds_msk[3][W_];        // 0.75 KB
    __shared__ float lds_sim[G_][W_][9];    // 18 KB
    __shared__ float lds_PT[G_][4][W_];     // 8 KB
    __shared__ float lds_attn[W_][9];       // 2.25 KB
    __shared__ float lds_Pf[4][W_];         // 1 KB
    __shared__ float lds_lam[W_];           // 0.25 KB

    const int t   = threadIdx.x;
    const int l   = t & 63;
    const int g   = t >> 6;
    const int sub = l >> 4;
    const int l16 = l & 15;
    const int w0  = l16 * 4;

    int b, h, s; decode_bhs(blockIdx.x, b, h, s);
    const int rowid = b * H_ + h;
    const int hm = (h > 0) ? h - 1 : 0;
    const int hp = (h < H_ - 1) ? h + 1 : H_ - 1;
    const size_t cs = (size_t)H_ * W_;
    const int c0 = s * CHALF + g * CPG;

    for (int i = t; i < 2 * C_; i += NT) lds_cw[i] = cw[i];
    if (t < 3 * W_) {
        const int r = t >> 6, col = t & 63;
        const int row = (r == 0) ? hm : ((r == 1) ? h : hp);
        lds_msk[r][col] = mask[((size_t)b * H_ + row) * W_ + col];
    }
    __syncthreads();

    const size_t base = (size_t)(b * C_ + c0) * H_;
    const size_t lo   = (size_t)sub * cs + w0;
    const float* ftp = Ft  + (base + h ) * W_ + lo;
    const float* q0p = Fwp + (base + hm) * W_ + lo;
    const float* q1p = Fwp + (base + h ) * W_ + lo;
    const float* q2p = Fwp + (base + hp) * W_ + lo;

    phase1_stream(ftp, q0p, q1p, q2p, lds_cw, c0, sub, l, l16, g, w0, t,
                  lds_sim, lds_PT, simp, ptp, (size_t)(rowid * 2 + s), cs);

    __threadfence();
    cg::this_grid().sync();     // all 512 blocks co-resident by coop launch

    phase2_out(ftp, q0p, q1p, q2p, out + (base + h) * W_ + lo,
               simp, ptp, cb, lds_msk, lds_attn, lds_Pf, lds_lam,
               t, l16, w0, (size_t)(rowid * 2), cs);
}

// ===========================================================================
// Fallback pair (round-11 proven): used only if cooperative launch fails.
__global__ __launch_bounds__(NT, 4) void k1_sim(
    const float* __restrict__ Ft, const float* __restrict__ Fwp,
    const float* __restrict__ cw,
    float* __restrict__ simp, float* __restrict__ ptp)
{
    __shared__ float lds_cw[2 * C_];
    __shared__ float lds_sim[G_][W_][9];
    __shared__ float lds_PT[G_][4][W_];

    const int t = threadIdx.x, l = t & 63, g = t >> 6;
    const int sub = l >> 4, l16 = l & 15, w0 = l16 * 4;
    int b, h, s; decode_bhs(blockIdx.x, b, h, s);
    const int hm = (h > 0) ? h - 1 : 0;
    const int hp = (h < H_ - 1) ? h + 1 : H_ - 1;
    const size_t cs = (size_t)H_ * W_;
    const int c0 = s * CHALF + g * CPG;

    for (int i = t; i < 2 * C_; i += NT) lds_cw[i] = cw[i];
    __syncthreads();

    const size_t base = (size_t)(b * C_ + c0) * H_;
    const size_t lo   = (size_t)sub * cs + w0;
    phase1_stream(Ft + (base + h) * W_ + lo, Fwp + (base + hm) * W_ + lo,
                  Fwp + (base + h) * W_ + lo, Fwp + (base + hp) * W_ + lo,
                  lds_cw, c0, sub, l, l16, g, w0, t,
                  lds_sim, lds_PT, simp, ptp,
                  (size_t)((b * H_ + h) * 2 + s), cs);
}

__global__ __launch_bounds__(NT, 4) void k2_out(
    const float* __restrict__ Ft, const float* __restrict__ Fwp,
    const float* __restrict__ mask, const float* __restrict__ cb,
    const float* __restrict__ simp, const float* __restrict__ ptp,
    float* __restrict__ out)
{
    __shared__ float lds_msk[3][W_];
    __shared__ float lds_attn[W_][9];
    __shared__ float lds_Pf[4][W_];
    __shared__ float lds_lam[W_];

    const int t = threadIdx.x, l = t & 63, g = t >> 6;
    const int sub = l >> 4, l16 = l & 15, w0 = l16 * 4;
    int b, h, s; decode_bhs(blockIdx.x, b, h, s);
    const int hm = (h > 0) ? h - 1 : 0;
    const int hp = (h < H_ - 1) ? h + 1 : H_ - 1;
    const size_t cs = (size_t)H_ * W_;
    const int c0 = s * CHALF + g * CPG;

    if (t < 3 * W_) {
        const int r = t >> 6, col = t & 63;
        const int row = (r == 0) ? hm : ((r == 1) ? h : hp);
        lds_msk[r][col] = mask[((size_t)b * H_ + row) * W_ + col];
    }
    __syncthreads();

    const size_t base = (size_t)(b * C_ + c0) * H_;
    const size_t lo   = (size_t)sub * cs + w0;
    phase2_out(Ft + (base + h) * W_ + lo, Fwp + (base + hm) * W_ + lo,
               Fwp + (base + h) * W_ + lo, Fwp + (base + hp) * W_ + lo,
               out + (base + h) * W_ + lo, simp, ptp, cb,
               lds_msk, lds_attn, lds_Pf, lds_lam,
               t, l16, w0, (size_t)((b * H_ + h) * 2), cs);
}

// ===========================================================================
extern "C" void kernel_launch(void* const* d_in, const int* in_sizes, int n_in,
                              void* d_out, int out_size, void* d_ws, size_t ws_size,
                              hipStream_t stream) {
    const float* Ft   = (const float*)d_in[0];
    const float* Fwp  = (const float*)d_in[1];
    const float* mask = (const float*)d_in[2];
    const float* cw   = (const float*)d_in[3];
    const float* cb   = (const float*)d_in[4];
    float* out = (float*)d_out;

    // ws layout (floats): simp[512][576] | ptp[512][256]  (~1.7 MB)
    float* simp = (float*)d_ws;
    float* ptp  = simp + (size_t)512 * (W_ * 9);

    dim3 grid(B_ * H_ * 2);   // 512 blocks = 2 blocks/CU
    dim3 block(NT);

    void* args[] = {(void*)&Ft, (void*)&Fwp, (void*)&mask, (void*)&cw,
                    (void*)&cb, (void*)&simp, (void*)&ptp, (void*)&out};
    hipError_t err = hipLaunchCooperativeKernel((void*)nca_coop, grid, block,
                                                args, 0, stream);
    if (err != hipSuccess) {
        // fallback: proven round-11 two-kernel pipeline
        k1_sim<<<grid, block, 0, stream>>>(Ft, Fwp, cw, simp, ptp);
        k2_out<<<grid, block, 0, stream>>>(Ft, Fwp, mask, cb, simp, ptp, out);
    }
}

// Round 14
// 42.285 us; speedup vs baseline: 3.9211x; 3.9211x over previous
//
#include <hip/hip_runtime.h>

#define B_  4
#define C_  640
#define H_  64
#define W_  64
#define G_  16          // channel groups (one wave each)
#define CPG 40          // channels per wave: G_*CPG == C_
#define NT  1024

// Accumulate one Fwarp row (4 px in r) against ft4 into a[12] (3 col-offsets x 4 px).
__device__ __forceinline__ void row_acc(const float4 ft4, const float4 r,
                                        const int l16, float* a) {
    const float pw = __shfl_up(r.w, 1, 64);     // lane l-1's elem 3
    const float nx = __shfl_down(r.x, 1, 64);   // lane l+1's elem 0
    const float vL0 = (l16 == 0)  ? r.x : pw;   // col 0 replicate
    const float vR3 = (l16 == 15) ? r.w : nx;   // col 63 replicate
    a[0]  = fmaf(ft4.x, vL0, a[0]);             // cc = col-1
    a[1]  = fmaf(ft4.y, r.x, a[1]);
    a[2]  = fmaf(ft4.z, r.y, a[2]);
    a[3]  = fmaf(ft4.w, r.z, a[3]);
    a[4]  = fmaf(ft4.x, r.x, a[4]);             // cc = center
    a[5]  = fmaf(ft4.y, r.y, a[5]);
    a[6]  = fmaf(ft4.z, r.z, a[6]);
    a[7]  = fmaf(ft4.w, r.w, a[7]);
    a[8]  = fmaf(ft4.x, r.y, a[8]);             // cc = col+1
    a[9]  = fmaf(ft4.y, r.z, a[9]);
    a[10] = fmaf(ft4.z, r.w, a[10]);
    a[11] = fmaf(ft4.w, vR3, a[11]);
}

// Weighted sum of one Fwarp row into fwv[4]; at = attn[4px][9], r3 = 3*row.
__device__ __forceinline__ void row_fw(const float4 r, const int l16,
                                       const float* at, const int r3, float* fwv) {
    const float pw = __shfl_up(r.w, 1, 64);
    const float nx = __shfl_down(r.x, 1, 64);
    const float vL0 = (l16 == 0)  ? r.x : pw;
    const float vR3 = (l16 == 15) ? r.w : nx;
    fwv[0] += at[0*9+r3]*vL0 + at[0*9+r3+1]*r.x + at[0*9+r3+2]*r.y;
    fwv[1] += at[1*9+r3]*r.x + at[1*9+r3+1]*r.y + at[1*9+r3+2]*r.z;
    fwv[2] += at[2*9+r3]*r.y + at[2*9+r3+1]*r.z + at[2*9+r3+2]*r.w;
    fwv[3] += at[3*9+r3]*r.z + at[3*9+r3+1]*r.w + at[3*9+r3+2]*vR3;
}

__global__ __launch_bounds__(NT, 4) void nca_fused(
    const float* __restrict__ Ft,
    const float* __restrict__ Fwp,
    const float* __restrict__ mask,
    const float* __restrict__ cw,
    const float* __restrict__ cb,
    float* __restrict__ out)
{
    __shared__ float lds_cw[2 * C_];        // 5 KB
    __shared__ float lds_msk[3][W_];        // 0.75 KB
    __shared__ float lds_sim[G_][W_][9];    // 36 KB
    __shared__ float lds_PT[G_][4][W_];     // 16 KB
    __shared__ float lds_attn[W_][9];       // 2.25 KB
    __shared__ float lds_Pf[4][W_];         // 1 KB
    __shared__ float lds_lam[W_];           // 0.25 KB
    // ~61.5 KB

    const int t   = threadIdx.x;
    const int l   = t & 63;
    const int g   = t >> 6;        // wave id = channel group
    const int sub = l >> 4;        // channel subgroup 0..3
    const int l16 = l & 15;
    const int w0  = l16 * 4;       // first pixel column of this lane

    // XCD-aware swizzle: XCD x owns rows [x*8, x*8+8) for all batches.
    const int n    = blockIdx.x + gridDim.x * blockIdx.y;
    const int slot = n >> 3;
    const int h = (n & 7) * 8 + (slot & 7);
    const int b = slot >> 3;

    const int hm = (h > 0) ? (h - 1) : 0;
    const int hp = (h < H_ - 1) ? (h + 1) : (H_ - 1);
    const size_t cs = (size_t)H_ * W_;
    const int c0 = g * CPG;

    for (int i = t; i < 2 * C_; i += NT) lds_cw[i] = cw[i];
    if (t < 3 * W_) {
        const int r = t >> 6, col = t & 63;
        const int row = (r == 0) ? hm : ((r == 1) ? h : hp);
        lds_msk[r][col] = mask[((size_t)b * H_ + row) * W_ + col];
    }
    __syncthreads();

    const size_t base = (size_t)(b * C_ + c0) * H_;
    const size_t lo   = (size_t)sub * cs + w0;
    const float* ftp = Ft  + (base + h ) * W_ + lo;
    const float* q0p = Fwp + (base + hm) * W_ + lo;
    const float* q1p = Fwp + (base + h ) * W_ + lo;
    const float* q2p = Fwp + (base + hp) * W_ + lo;

    // ---- Pass A + P/T fused: ONE streaming walk ---------------------------
    float acc[36], Pp[12], T4[4];
    #pragma unroll
    for (int i = 0; i < 36; ++i) acc[i] = 0.f;
    #pragma unroll
    for (int i = 0; i < 12; ++i) Pp[i] = 0.f;
    #pragma unroll
    for (int i = 0; i < 4; ++i) T4[i] = 0.f;

    #pragma unroll 4
    for (int k = 0; k < CPG; k += 4) {
        const size_t off = (size_t)k * cs;
        const float4 ft4 = *(const float4*)(ftp + off);
        const float4 r0  = *(const float4*)(q0p + off);
        const float4 r1  = *(const float4*)(q1p + off);
        const float4 r2  = *(const float4*)(q2p + off);
        row_acc(ft4, r0, l16, &acc[0]);
        row_acc(ft4, r1, l16, &acc[12]);
        row_acc(ft4, r2, l16, &acc[24]);
        const int c = c0 + k + sub;
        const float wF = lds_cw[c];
        const float wT = lds_cw[C_ + c];
        Pp[0] = fmaf(wF, r0.x, Pp[0]); Pp[1]  = fmaf(wF, r0.y, Pp[1]);
        Pp[2] = fmaf(wF, r0.z, Pp[2]); Pp[3]  = fmaf(wF, r0.w, Pp[3]);
        Pp[4] = fmaf(wF, r1.x, Pp[4]); Pp[5]  = fmaf(wF, r1.y, Pp[5]);
        Pp[6] = fmaf(wF, r1.z, Pp[6]); Pp[7]  = fmaf(wF, r1.w, Pp[7]);
        Pp[8] = fmaf(wF, r2.x, Pp[8]); Pp[9]  = fmaf(wF, r2.y, Pp[9]);
        Pp[10]= fmaf(wF, r2.z, Pp[10]);Pp[11] = fmaf(wF, r2.w, Pp[11]);
        T4[0] = fmaf(wT, ft4.x, T4[0]); T4[1] = fmaf(wT, ft4.y, T4[1]);
        T4[2] = fmaf(wT, ft4.z, T4[2]); T4[3] = fmaf(wT, ft4.w, T4[3]);
    }

    // reduce the 4 channel-subgroups (lanes l, l^16, l^32, l^48)
    #pragma unroll
    for (int i = 0; i < 36; ++i) {
        acc[i] += __shfl_xor(acc[i], 16, 64);
        acc[i] += __shfl_xor(acc[i], 32, 64);
    }
    #pragma unroll
    for (int i = 0; i < 12; ++i) {
        Pp[i] += __shfl_xor(Pp[i], 16, 64);
        Pp[i] += __shfl_xor(Pp[i], 32, 64);
    }
    #pragma unroll
    for (int i = 0; i < 4; ++i) {
        T4[i] += __shfl_xor(T4[i], 16, 64);
        T4[i] += __shfl_xor(T4[i], 32, 64);
    }

    // STATIC-index LDS write (rule #20: px is an unroll constant)
    if (l < 16) {
        #pragma unroll
        for (int px = 0; px < 4; ++px) {
            #pragma unroll
            for (int r = 0; r < 3; ++r) {
                #pragma unroll
                for (int cc = 0; cc < 3; ++cc)
                    lds_sim[g][w0 + px][r * 3 + cc] = acc[r * 12 + cc * 4 + px];
                lds_PT[g][r][w0 + px] = Pp[r * 4 + px];
            }
            lds_PT[g][3][w0 + px] = T4[px];
        }
    }
    __syncthreads();

    // ---- reduce across waves + mask; P/T reduce in parallel threads -------
    if (t < W_ * 9) {
        const int ww = t / 9, q = t % 9;
        float s = 0.f;
        #pragma unroll
        for (int gg = 0; gg < G_; ++gg) s += lds_sim[gg][ww][q];
        s *= 0.03952847075210474f;          // 1/sqrt(640)
        const int r = q / 3, j = q % 3;
        int col = ww + j - 1;
        col = col < 0 ? 0 : (col > W_ - 1 ? W_ - 1 : col);
        if (lds_msk[r][col] == 1.0f) s = -1e9f;
        lds_attn[ww][q] = s;
    } else if (t >= 640 && t < 640 + 256) {
        const int idx = t - 640;
        const int r = idx >> 6, ww = idx & 63;
        float s = 0.f;
        #pragma unroll
        for (int gg = 0; gg < G_; ++gg) s += lds_PT[gg][r][ww];
        lds_Pf[r][ww] = s;
    }
    __syncthreads();

    // ---- softmax per pixel + lambda via P-trick ---------------------------
    if (t < W_) {
        float v[9];
        float mx = -3e38f;
        bool valid = false;
        #pragma unroll
        for (int q = 0; q < 9; ++q) {
            v[q] = lds_attn[t][q];
            if (v[q] > -5e8f) valid = true;
            mx = fmaxf(mx, v[q]);
        }
        float a9[9];
        if (!valid) {
            #pragma unroll
            for (int q = 0; q < 9; ++q) a9[q] = 0.f;
        } else {
            float sum = 0.f;
            #pragma unroll
            for (int q = 0; q < 9; ++q) { a9[q] = expf(v[q] - mx); sum += a9[q]; }
            const float inv = 1.f / sum;
            #pragma unroll
            for (int q = 0; q < 9; ++q) a9[q] *= inv;
        }
        #pragma unroll
        for (int q = 0; q < 9; ++q) lds_attn[t][q] = a9[q];

        float lamF = 0.f;
        #pragma unroll
        for (int r = 0; r < 3; ++r)
            #pragma unroll
            for (int j = 0; j < 3; ++j) {
                int col = t + j - 1;
                col = col < 0 ? 0 : (col > W_ - 1 ? W_ - 1 : col);
                lamF = fmaf(a9[r * 3 + j], lds_Pf[r][col], lamF);
            }
        const float d = lds_Pf[3][t] + lamF + cb[0];
        lds_lam[t] = 1.f / (1.f + expf(-d));
    }
    __syncthreads();

    // ---- Pass BC: fwv + blend + store (ONE walk, streams cache-warm) ------
    float at[36];
    #pragma unroll
    for (int px = 0; px < 4; ++px)
        #pragma unroll
        for (int q = 0; q < 9; ++q) at[px * 9 + q] = lds_attn[w0 + px][q];
    float lam4[4], oml4[4];
    #pragma unroll
    for (int px = 0; px < 4; ++px) {
        lam4[px] = lds_lam[w0 + px];
        oml4[px] = 1.f - lam4[px];
    }

    float* outp = out + (base + h) * W_ + lo;
    #pragma unroll 2
    for (int k = 0; k < CPG; k += 4) {
        const size_t off = (size_t)k * cs;
        const float4 ft4 = *(const float4*)(ftp + off);
        const float4 r0  = *(const float4*)(q0p + off);
        const float4 r1  = *(const float4*)(q1p + off);
        const float4 r2  = *(const float4*)(q2p + off);
        float fwv[4] = {0.f, 0.f, 0.f, 0.f};
        row_fw(r0, l16, at, 0, fwv);
        row_fw(r1, l16, at, 3, fwv);
        row_fw(r2, l16, at, 6, fwv);
        float4 o;
        o.x = lam4[0] * ft4.x + oml4[0] * fwv[0];
        o.y = lam4[1] * ft4.y + oml4[1] * fwv[1];
        o.z = lam4[2] * ft4.z + oml4[2] * fwv[2];
        o.w = lam4[3] * ft4.w + oml4[3] * fwv[3];
        *(float4*)(outp + off) = o;
    }
}

extern "C" void kernel_launch(void* const* d_in, const int* in_sizes, int n_in,
                              void* d_out, int out_size, void* d_ws, size_t ws_size,
                              hipStream_t stream) {
    const float* Ft   = (const float*)d_in[0];
    const float* Fwp  = (const float*)d_in[1];
    const float* mask = (const float*)d_in[2];
    const float* cw   = (const float*)d_in[3];
    const float* cb   = (const float*)d_in[4];
    float* out = (float*)d_out;

    dim3 grid(H_, B_);   // 256 blocks == 256 CUs
    dim3 block(NT);
    nca_fused<<<grid, block, 0, stream>>>(Ft, Fwp, mask, cw, cb, out);
}